// Round 2
// baseline (391.723 us; speedup 1.0000x reference)
//
#include <hip/hip_runtime.h>
#include <hip/hip_bf16.h>

#define THREADS 256
#define MTILE   64      // batch rows per block
#define HID     128
#define BATCH   32768
#define NFEAT   8

typedef __attribute__((ext_vector_type(4))) float f32x4;
typedef __attribute__((ext_vector_type(8))) short s16x8;

struct Ptrs {
    const float* feat[NFEAT];
    const float* wk[NFEAT];
    const float* wv[NFEAT];
    const float* q;
};

__device__ __forceinline__ float bf2f(unsigned short u) {
    union { unsigned int i; float f; } c; c.i = ((unsigned int)u) << 16; return c.f;
}
__device__ __forceinline__ unsigned short f2bf(float f) {
    union { __hip_bfloat16 h; unsigned short u; } c; c.h = __float2bfloat16(f); return c.u;
}

// ---------------- prep: qk_i = (Wk_i^T q) / sqrt(128), into d_ws ----------------
__device__ const int g_fdim[NFEAT] = {32, 64, 96, 128, 192, 256, 384, 512};
__device__ const int g_foff[NFEAT] = {0, 32, 96, 192, 320, 512, 768, 1152};

__global__ void prep_qk(Ptrs p, float* qk) {
    int i = blockIdx.x;
    int d = g_fdim[i];
    const float* Wk = p.wk[i];
    const float* q  = p.q;
    for (int c = threadIdx.x; c < d; c += blockDim.x) {
        float s = 0.f;
        for (int h = 0; h < HID; ++h) s = fmaf(q[h], Wk[h * d + c], s);
        qk[g_foff[i] + c] = s * 0.08838834764831845f;   // 1/sqrt(128)
    }
}

// ---------------- main fused kernel ----------------
// Per feature chunk (DC <= 256 cols):
//   stage 64 x DC fp32 -> bf16 LDS (feats read once from HBM)
//   score partials from LDS (4 threads/row)
//   P += A_chunk @ Wv_chunk^T via mfma 16x16x32 bf16 (B fp32 from L2, cvt inline)
// On last chunk of a feature: w = exp(s); Z += w; O += w * P.
template<int FI, int D, int FOFFV, int CK0, int DC, bool FIRST, bool LAST>
__device__ __forceinline__ void process_chunk(
    const Ptrs& p, const float* qk,
    unsigned short* A, float* wAll, float* Zrow,
    float& spart, f32x4 (&P)[4][2], f32x4 (&O)[4][2],
    int tid, int wave, int l15, int q4, int row0)
{
    constexpr int SD = DC + 8;   // +8 bf16 pad -> dword stride == 4 (mod 8): 2-way banks (free)

    if (FIRST) {
        spart = 0.f;
        #pragma unroll
        for (int mt = 0; mt < 4; ++mt) {
            P[mt][0] = f32x4{0.f, 0.f, 0.f, 0.f};
            P[mt][1] = f32x4{0.f, 0.f, 0.f, 0.f};
        }
    }

    // ---- stage: coalesced float4 global reads, bf16 LDS writes ----
    {
        const float* fbase = p.feat[FI] + (size_t)row0 * D + CK0;
        constexpr int NITER = (MTILE * DC / 4) / THREADS;   // exact: DC multiple of 32
        #pragma unroll
        for (int jj = 0; jj < NITER; ++jj) {
            int j = tid + jj * THREADS;
            int flat = j * 4;
            int r = flat / DC;
            int c = flat - r * DC;
            float4 v = *reinterpret_cast<const float4*>(fbase + (size_t)r * D + c);
            ushort4 u;
            u.x = f2bf(v.x); u.y = f2bf(v.y); u.z = f2bf(v.z); u.w = f2bf(v.w);
            *reinterpret_cast<ushort4*>(&A[r * SD + c]) = u;
        }
    }
    __syncthreads();

    // ---- score partial: 4 threads per row ----
    {
        int r = tid >> 2, part = tid & 3;
        constexpr int Q = DC / 4;
        const float* qf = qk + FOFFV + CK0 + part * Q;
        const unsigned short* arow = A + r * SD + part * Q;
        float acc = 0.f;
        #pragma unroll 4
        for (int c = 0; c < Q; c += 4) {
            ushort4 u  = *reinterpret_cast<const ushort4*>(arow + c);
            float4  qv = *reinterpret_cast<const float4*>(qf + c);
            acc += bf2f(u.x) * qv.x + bf2f(u.y) * qv.y +
                   bf2f(u.z) * qv.z + bf2f(u.w) * qv.w;
        }
        spart += acc;
    }

    // ---- MFMA: P += A @ Wv^T over this chunk's K ----
    {
        const float* Wv = p.wv[FI];
        #pragma unroll 2
        for (int kk = 0; kk < DC / 32; ++kk) {
            int k0 = kk * 32 + q4 * 8;
            s16x8 bfrag[2];
            #pragma unroll
            for (int nt = 0; nt < 2; ++nt) {
                int h = wave * 32 + nt * 16 + l15;          // B[k][n]: n = lane&15, k = quad*8+j
                const float* src = Wv + h * D + CK0 + k0;   // 8 consecutive k (contiguous in Wv row)
                float4 x = *reinterpret_cast<const float4*>(src);
                float4 y = *reinterpret_cast<const float4*>(src + 4);
                s16x8 b;
                b[0] = (short)f2bf(x.x); b[1] = (short)f2bf(x.y);
                b[2] = (short)f2bf(x.z); b[3] = (short)f2bf(x.w);
                b[4] = (short)f2bf(y.x); b[5] = (short)f2bf(y.y);
                b[6] = (short)f2bf(y.z); b[7] = (short)f2bf(y.w);
                bfrag[nt] = b;
            }
            #pragma unroll
            for (int mt = 0; mt < 4; ++mt) {
                // A[m][k]: m = lane&15, k = quad*8+j  -> ds_read_b128
                s16x8 a = *reinterpret_cast<const s16x8*>(A + (mt * 16 + l15) * SD + k0);
                P[mt][0] = __builtin_amdgcn_mfma_f32_16x16x32_bf16(a, bfrag[0], P[mt][0], 0, 0, 0);
                P[mt][1] = __builtin_amdgcn_mfma_f32_16x16x32_bf16(a, bfrag[1], P[mt][1], 0, 0, 0);
            }
        }
    }
    __syncthreads();   // A safe to overwrite by next chunk

    if (LAST) {
        // finalize score for this feature, fold P into O with w = exp(s)
        float s = spart;
        s += __shfl_xor(s, 1, 64);
        s += __shfl_xor(s, 2, 64);
        int r = tid >> 2;
        if ((tid & 3) == 0) {
            float w = __expf(s);              // scores ~ N(0,1/3): no max-subtraction needed
            wAll[FI * MTILE + r] = w;
            Zrow[r] += w;
        }
        __syncthreads();
        #pragma unroll
        for (int mt = 0; mt < 4; ++mt) {
            #pragma unroll
            for (int rr = 0; rr < 4; ++rr) {
                // C/D layout: col = lane&15, row = quad*4 + reg
                float w = wAll[FI * MTILE + mt * 16 + q4 * 4 + rr];
                O[mt][0][rr] += w * P[mt][0][rr];
                O[mt][1][rr] += w * P[mt][1][rr];
            }
        }
    }
}

__global__ __launch_bounds__(THREADS, 2)
void attn_main(Ptrs p, const float* qk, float* outC, float* outA) {
    __shared__ __align__(16) unsigned short Abuf[MTILE * (256 + 8)];   // 33.8 KB
    __shared__ float wAll[NFEAT * MTILE];                              // exp(s) per feature/row
    __shared__ float Zrow[MTILE];

    int tid  = threadIdx.x;
    int wave = tid >> 6;
    int lane = tid & 63;
    int l15  = lane & 15, q4 = lane >> 4;
    int row0 = blockIdx.x * MTILE;

    if (tid < MTILE) Zrow[tid] = 0.f;

    f32x4 P[4][2], O[4][2];
    #pragma unroll
    for (int mt = 0; mt < 4; ++mt) {
        O[mt][0] = f32x4{0.f, 0.f, 0.f, 0.f};
        O[mt][1] = f32x4{0.f, 0.f, 0.f, 0.f};
    }
    float spart = 0.f;

    //            FI   D   FOFF  CK0  DC   FIRST LAST
    process_chunk<0,  32,    0,   0,  32,  true, true >(p, qk, Abuf, wAll, Zrow, spart, P, O, tid, wave, l15, q4, row0);
    process_chunk<1,  64,   32,   0,  64,  true, true >(p, qk, Abuf, wAll, Zrow, spart, P, O, tid, wave, l15, q4, row0);
    process_chunk<2,  96,   96,   0,  96,  true, true >(p, qk, Abuf, wAll, Zrow, spart, P, O, tid, wave, l15, q4, row0);
    process_chunk<3, 128,  192,   0, 128,  true, true >(p, qk, Abuf, wAll, Zrow, spart, P, O, tid, wave, l15, q4, row0);
    process_chunk<4, 192,  320,   0, 192,  true, true >(p, qk, Abuf, wAll, Zrow, spart, P, O, tid, wave, l15, q4, row0);
    process_chunk<5, 256,  512,   0, 256,  true, true >(p, qk, Abuf, wAll, Zrow, spart, P, O, tid, wave, l15, q4, row0);
    process_chunk<6, 384,  768,   0, 256,  true, false>(p, qk, Abuf, wAll, Zrow, spart, P, O, tid, wave, l15, q4, row0);
    process_chunk<6, 384,  768, 256, 128, false, true >(p, qk, Abuf, wAll, Zrow, spart, P, O, tid, wave, l15, q4, row0);
    process_chunk<7, 512, 1152,   0, 256,  true, false>(p, qk, Abuf, wAll, Zrow, spart, P, O, tid, wave, l15, q4, row0);
    process_chunk<7, 512, 1152, 256, 256, false, true >(p, qk, Abuf, wAll, Zrow, spart, P, O, tid, wave, l15, q4, row0);

    // ---- epilogue: combined = O / Z ; attn = w / Z ----
    #pragma unroll
    for (int mt = 0; mt < 4; ++mt) {
        #pragma unroll
        for (int rr = 0; rr < 4; ++rr) {
            int row = mt * 16 + q4 * 4 + rr;
            float zi = 1.0f / Zrow[row];
            int gr = row0 + row;
            outC[gr * HID + wave * 32 + l15]      = O[mt][0][rr] * zi;
            outC[gr * HID + wave * 32 + 16 + l15] = O[mt][1][rr] * zi;
        }
    }
    if (tid < MTILE) {
        float zi = 1.0f / Zrow[tid];
        int gr = row0 + tid;
        #pragma unroll
        for (int i = 0; i < NFEAT; ++i)
            outA[gr * NFEAT + i] = wAll[i * MTILE + tid] * zi;
    }
}

extern "C" void kernel_launch(void* const* d_in, const int* in_sizes, int n_in,
                              void* d_out, int out_size, void* d_ws, size_t ws_size,
                              hipStream_t stream) {
    Ptrs p;
    // setup_inputs() dict order: feat0..feat7, then Wk0,Wv0,Wk1,Wv1,... (interleaved!), then query
    for (int i = 0; i < NFEAT; ++i) {
        p.feat[i] = (const float*)d_in[i];
        p.wk[i]   = (const float*)d_in[NFEAT + 2 * i];
        p.wv[i]   = (const float*)d_in[NFEAT + 2 * i + 1];
    }
    p.q = (const float*)d_in[3 * NFEAT];

    float* qk = (float*)d_ws;   // 1664 floats
    prep_qk<<<NFEAT, 256, 0, stream>>>(p, qk);

    float* outC = (float*)d_out;
    float* outA = outC + (size_t)BATCH * HID;
    attn_main<<<BATCH / MTILE, THREADS, 0, stream>>>(p, qk, outC, outA);
}

// Round 3
// 349.338 us; speedup vs baseline: 1.1213x; 1.1213x over previous
//
#include <hip/hip_runtime.h>
#include <hip/hip_bf16.h>

#define THREADS 256
#define MTILE   32      // batch rows per block
#define HID     128
#define BATCH   32768
#define NFEAT   8
#define SDMAX   264     // max LDS row stride (256 + 8 pad)

typedef __attribute__((ext_vector_type(4))) float f32x4;
typedef __attribute__((ext_vector_type(8))) short s16x8;

struct Ptrs {
    const float* feat[NFEAT];
    const float* wk[NFEAT];
    const float* wv[NFEAT];
    const float* q;
};

__device__ __forceinline__ float bf2f(unsigned short u) {
    union { unsigned int i; float f; } c; c.i = ((unsigned int)u) << 16; return c.f;
}
__device__ __forceinline__ unsigned short f2bf(float f) {
    union { __hip_bfloat16 h; unsigned short u; } c; c.h = __float2bfloat16(f); return c.u;
}

__device__ const int g_fdim[NFEAT] = {32, 64, 96, 128, 192, 256, 384, 512};
__device__ const int g_foff[NFEAT] = {0, 32, 96, 192, 320, 512, 768, 1152};

// ---------------- prep 1: qk_i = (Wk_i^T q) / sqrt(128) ----------------
__global__ void prep_qk(Ptrs p, float* qk) {
    int i = blockIdx.x;
    int d = g_fdim[i];
    const float* Wk = p.wk[i];
    const float* q  = p.q;
    for (int c = threadIdx.x; c < d; c += blockDim.x) {
        float s = 0.f;
        #pragma unroll 8
        for (int h = 0; h < HID; ++h) s = fmaf(q[h], Wk[h * d + c], s);
        qk[g_foff[i] + c] = s * 0.08838834764831845f;   // 1/sqrt(128)
    }
}

// ---------------- prep 2: Wv -> bf16 in B-fragment layout ----------------
// WvB[128*foff[fi] + (kg*128 + h)*8 + j] = bf16(Wv[h*D + kg*8 + j])
// so a lane's B-frag (h, k0..k0+7) is ONE contiguous 16B load, coalesced across lanes.
__global__ void prep_wv(Ptrs p, unsigned short* WvB) {
    int fi    = blockIdx.x >> 3;
    int slice = blockIdx.x & 7;
    int D  = g_fdim[fi];
    int Dg = D >> 3;
    const float* Wv = p.wv[fi];
    unsigned short* out = WvB + 128 * g_foff[fi];
    int h0  = slice * 16;
    int cnt = 16 * Dg;
    for (int e = threadIdx.x; e < cnt; e += blockDim.x) {
        int h  = h0 + e / Dg;
        int kg = e - (e / Dg) * Dg;
        const float* src = Wv + h * D + kg * 8;
        float4 x = *reinterpret_cast<const float4*>(src);
        float4 y = *reinterpret_cast<const float4*>(src + 4);
        s16x8 b;
        b[0] = (short)f2bf(x.x); b[1] = (short)f2bf(x.y);
        b[2] = (short)f2bf(x.z); b[3] = (short)f2bf(x.w);
        b[4] = (short)f2bf(y.x); b[5] = (short)f2bf(y.y);
        b[6] = (short)f2bf(y.z); b[7] = (short)f2bf(y.w);
        *reinterpret_cast<s16x8*>(out + (kg * 128 + h) * 8) = b;
    }
}

// ---------------- main kernel pieces ----------------
template<int FI, int D, int CK0, int DC>
__device__ __forceinline__ void stage_issue(const Ptrs& p, int row0, int tid, float4* regs) {
    const float* fbase = p.feat[FI] + (size_t)row0 * D + CK0;
    constexpr int NITER = (MTILE * DC / 4) / THREADS;   // = DC/32, <= 8
    #pragma unroll
    for (int jj = 0; jj < NITER; ++jj) {
        int flat = (tid + jj * THREADS) * 4;
        int r = flat / DC;
        int c = flat - r * DC;
        regs[jj] = *reinterpret_cast<const float4*>(fbase + (size_t)r * D + c);
    }
}

template<int DC>
__device__ __forceinline__ void stage_commit(const float4* regs, unsigned short* A, int tid) {
    constexpr int SD = DC + 8;
    constexpr int NITER = (MTILE * DC / 4) / THREADS;
    #pragma unroll
    for (int jj = 0; jj < NITER; ++jj) {
        int flat = (tid + jj * THREADS) * 4;
        int r = flat / DC;
        int c = flat - r * DC;
        float4 v = regs[jj];
        ushort4 u;
        u.x = f2bf(v.x); u.y = f2bf(v.y); u.z = f2bf(v.z); u.w = f2bf(v.w);
        *reinterpret_cast<ushort4*>(&A[r * SD + c]) = u;
    }
}

template<int FI, int FOFF, int CK0, int DC, bool FIRST, bool LAST>
__device__ __forceinline__ void compute_chunk(
    const unsigned short* A, const unsigned short* WvB, const float* qk,
    float* wAll, float* Zrow, float& spart,
    f32x4 (&P)[2][2], f32x4 (&O)[2][2],
    int tid, int wave, int l15, int q4)
{
    constexpr int SD = DC + 8;
    if (FIRST) {
        spart = 0.f;
        #pragma unroll
        for (int mt = 0; mt < 2; ++mt) {
            P[mt][0] = f32x4{0.f, 0.f, 0.f, 0.f};
            P[mt][1] = f32x4{0.f, 0.f, 0.f, 0.f};
        }
    }

    // ---- score partial: 8 threads per row ----
    {
        int r = tid >> 3, part = tid & 7;
        constexpr int Q = DC / 8;   // multiple of 4
        const float* qf = qk + FOFF + CK0 + part * Q;   // tiny, L1-hot
        const unsigned short* arow = A + r * SD + part * Q;
        float acc = 0.f;
        #pragma unroll
        for (int c = 0; c < Q; c += 4) {
            ushort4 u  = *reinterpret_cast<const ushort4*>(arow + c);
            float4  qv = *reinterpret_cast<const float4*>(qf + c);
            acc += bf2f(u.x) * qv.x + bf2f(u.y) * qv.y +
                   bf2f(u.z) * qv.z + bf2f(u.w) * qv.w;
        }
        spart += acc;
    }

    // ---- MFMA: P += A @ Wv^T (B pre-converted bf16, fragment layout) ----
    {
        const unsigned short* Wb = WvB + 128 * FOFF;
        #pragma unroll
        for (int kk = 0; kk < DC / 32; ++kk) {
            int kg = CK0 / 8 + kk * 4 + q4;
            int hb = wave * 32 + l15;
            s16x8 b0 = *reinterpret_cast<const s16x8*>(Wb + (kg * 128 + hb) * 8);
            s16x8 b1 = *reinterpret_cast<const s16x8*>(Wb + (kg * 128 + hb + 16) * 8);
            int k0 = kk * 32 + q4 * 8;
            #pragma unroll
            for (int mt = 0; mt < 2; ++mt) {
                s16x8 a = *reinterpret_cast<const s16x8*>(A + (mt * 16 + l15) * SD + k0);
                P[mt][0] = __builtin_amdgcn_mfma_f32_16x16x32_bf16(a, b0, P[mt][0], 0, 0, 0);
                P[mt][1] = __builtin_amdgcn_mfma_f32_16x16x32_bf16(a, b1, P[mt][1], 0, 0, 0);
            }
        }
    }

    if (LAST) {
        float s = spart;
        s += __shfl_xor(s, 1, 64);
        s += __shfl_xor(s, 2, 64);
        s += __shfl_xor(s, 4, 64);
        int r = tid >> 3;
        if ((tid & 7) == 0) {
            float w = __expf(s);        // scores ~ N(0,1/3): no max-subtraction needed
            wAll[FI * MTILE + r] = w;
            Zrow[r] += w;
        }
        __syncthreads();
        #pragma unroll
        for (int mt = 0; mt < 2; ++mt) {
            #pragma unroll
            for (int rr = 0; rr < 4; ++rr) {
                // C/D layout: col = lane&15, row = quad*4 + reg
                float w = wAll[FI * MTILE + mt * 16 + q4 * 4 + rr];
                O[mt][0][rr] += w * P[mt][0][rr];
                O[mt][1][rr] += w * P[mt][1][rr];
            }
        }
    }
}

__global__ __launch_bounds__(THREADS, 4)
void attn_main(Ptrs p, const unsigned short* WvB, const float* qk,
               float* outC, float* outA) {
    __shared__ __align__(16) unsigned short Abuf[2 * MTILE * SDMAX];  // 33.8 KB
    __shared__ float wAll[NFEAT * MTILE];
    __shared__ float Zrow[MTILE];
    unsigned short* buf0 = Abuf;
    unsigned short* buf1 = Abuf + MTILE * SDMAX;

    int tid  = threadIdx.x;
    int wave = tid >> 6;
    int lane = tid & 63;
    int l15  = lane & 15, q4 = lane >> 4;
    int row0 = blockIdx.x * MTILE;

    if (tid < MTILE) Zrow[tid] = 0.f;

    f32x4 P[2][2], O[2][2];
    #pragma unroll
    for (int mt = 0; mt < 2; ++mt) {
        O[mt][0] = f32x4{0.f, 0.f, 0.f, 0.f};
        O[mt][1] = f32x4{0.f, 0.f, 0.f, 0.f};
    }
    float spart = 0.f;
    float4 regs[8];

#define ISSUE(FI,D,CK0,DC)                stage_issue<FI,D,CK0,DC>(p, row0, tid, regs)
#define COMMIT(DC,BUF)                    stage_commit<DC>(regs, BUF, tid)
#define COMP(FI,FOFF,CK0,DC,FIRST,LAST,BUF) \
    compute_chunk<FI,FOFF,CK0,DC,FIRST,LAST>(BUF, WvB, qk, wAll, Zrow, spart, P, O, tid, wave, l15, q4)

    // Software pipeline: issue(c+1) -> compute(c) -> commit(c+1) -> barrier.
    // Chunk c lives in buf(c%2); compute(c) and commit(c+1) touch opposite buffers.
    ISSUE(0,  32,   0,  32);                                          COMMIT( 32, buf0); __syncthreads();
    ISSUE(1,  64,   0,  64); COMP(0,    0,   0,  32, true,  true,  buf0); COMMIT( 64, buf1); __syncthreads();
    ISSUE(2,  96,   0,  96); COMP(1,   32,   0,  64, true,  true,  buf1); COMMIT( 96, buf0); __syncthreads();
    ISSUE(3, 128,   0, 128); COMP(2,   96,   0,  96, true,  true,  buf0); COMMIT(128, buf1); __syncthreads();
    ISSUE(4, 192,   0, 192); COMP(3,  192,   0, 128, true,  true,  buf1); COMMIT(192, buf0); __syncthreads();
    ISSUE(5, 256,   0, 256); COMP(4,  320,   0, 192, true,  true,  buf0); COMMIT(256, buf1); __syncthreads();
    ISSUE(6, 384,   0, 256); COMP(5,  512,   0, 256, true,  true,  buf1); COMMIT(256, buf0); __syncthreads();
    ISSUE(6, 384, 256, 128); COMP(6,  768,   0, 256, true,  false, buf0); COMMIT(128, buf1); __syncthreads();
    ISSUE(7, 512,   0, 256); COMP(6,  768, 256, 128, false, true,  buf1); COMMIT(256, buf0); __syncthreads();
    ISSUE(7, 512, 256, 256); COMP(7, 1152,   0, 256, true,  false, buf0); COMMIT(256, buf1); __syncthreads();
                             COMP(7, 1152, 256, 256, false, true,  buf1);

    // ---- epilogue: transpose O through LDS, coalesced float4 stores ----
    __syncthreads();                       // all waves done reading buf1
    float* Ctmp = reinterpret_cast<float*>(Abuf);   // 32 x 136 fp32 = 17.4 KB
    #pragma unroll
    for (int mt = 0; mt < 2; ++mt) {
        #pragma unroll
        for (int rr = 0; rr < 4; ++rr) {
            int row = mt * 16 + q4 * 4 + rr;
            float zi = 1.0f / Zrow[row];
            Ctmp[row * 136 + wave * 32 + l15]      = O[mt][0][rr] * zi;
            Ctmp[row * 136 + wave * 32 + 16 + l15] = O[mt][1][rr] * zi;
        }
    }
    __syncthreads();
    #pragma unroll
    for (int it = 0; it < 4; ++it) {
        int j = tid + it * THREADS;        // 0..1023 = 32 rows x 32 float4
        int r = j >> 5, c4 = (j & 31) * 4;
        *reinterpret_cast<float4*>(outC + (size_t)(row0 + r) * HID + c4) =
            *reinterpret_cast<const float4*>(Ctmp + r * 136 + c4);
    }
    if (tid < MTILE) {
        float zi = 1.0f / Zrow[tid];
        float4 a0, a1;
        a0.x = wAll[0 * MTILE + tid] * zi; a0.y = wAll[1 * MTILE + tid] * zi;
        a0.z = wAll[2 * MTILE + tid] * zi; a0.w = wAll[3 * MTILE + tid] * zi;
        a1.x = wAll[4 * MTILE + tid] * zi; a1.y = wAll[5 * MTILE + tid] * zi;
        a1.z = wAll[6 * MTILE + tid] * zi; a1.w = wAll[7 * MTILE + tid] * zi;
        float* dst = outA + (size_t)(row0 + tid) * NFEAT;
        *reinterpret_cast<float4*>(dst)     = a0;
        *reinterpret_cast<float4*>(dst + 4) = a1;
    }
#undef ISSUE
#undef COMMIT
#undef COMP
}

extern "C" void kernel_launch(void* const* d_in, const int* in_sizes, int n_in,
                              void* d_out, int out_size, void* d_ws, size_t ws_size,
                              hipStream_t stream) {
    Ptrs p;
    // setup_inputs() dict order: feat0..feat7, then Wk0,Wv0,Wk1,Wv1,... (interleaved), then query
    for (int i = 0; i < NFEAT; ++i) {
        p.feat[i] = (const float*)d_in[i];
        p.wk[i]   = (const float*)d_in[NFEAT + 2 * i];
        p.wv[i]   = (const float*)d_in[NFEAT + 2 * i + 1];
    }
    p.q = (const float*)d_in[3 * NFEAT];

    // workspace layout: [WvB bf16: 128*1664*2 = 425984 B][qk fp32: 1664*4 B]
    unsigned short* WvB = (unsigned short*)d_ws;
    float* qk = (float*)((char*)d_ws + 128 * 1664 * 2);

    prep_wv<<<NFEAT * 8, 256, 0, stream>>>(p, WvB);
    prep_qk<<<NFEAT, 256, 0, stream>>>(p, qk);

    float* outC = (float*)d_out;
    float* outA = outC + (size_t)BATCH * HID;
    attn_main<<<BATCH / MTILE, THREADS, 0, stream>>>(p, WvB, qk, outC, outA);
}